// Round 6
// baseline (409.037 us; speedup 1.0000x reference)
//
#include <hip/hip_runtime.h>
#include <hip/hip_cooperative_groups.h>

namespace cg = cooperative_groups;

// T=8192 rows, H=4096 cols, f32 inputs.
// Outputs concat: [ q_dyn (T*H, f32-widened fp8), residual_out (T*H, f32) ]
//
// Cooperative single-kernel, register-lean (R5 spilled av[16] -> scratch):
//   RPW=1: 2048 blocks x 256 thr, one row per wave, NO row state held.
//   Trip1: stream h+r -> resid_out, f64 sumsq, wave shfl reduce (no barrier).
//   Trip2: re-read resid_out (L2/L3 hot) + w -> static quant -> q8 in ws.
//   grid.sync -> global amax -> 256-entry LDS LUT (one divide per byte value)
//   -> pass2: byte unpack + LUT + nt-store. No divides in the hot loop.

typedef float v2f __attribute__((ext_vector_type(2)));
typedef float v4f __attribute__((ext_vector_type(4)));

static constexpr int H_DIM = 4096;
#define FP8_MAX_F 448.0f

__device__ __forceinline__ unsigned int quant4(float q0, float q1, float q2, float q3) {
    unsigned int pk = 0;
    pk = __builtin_amdgcn_cvt_pk_fp8_f32(q0, q1, pk, false); // bytes 0,1
    pk = __builtin_amdgcn_cvt_pk_fp8_f32(q2, q3, pk, true);  // bytes 2,3
    return pk;
}

__device__ __forceinline__ float fp8_roundtrip1(float x) {
    unsigned int pk = __builtin_amdgcn_cvt_pk_fp8_f32(x, x, 0, false);
    v2f d = __builtin_amdgcn_cvt_pk_f32_fp8((int)pk, false);
    return d[0];
}

__device__ __forceinline__ float fp8_byte_to_f32(unsigned int b) {
    v2f d = __builtin_amdgcn_cvt_pk_f32_fp8((int)b, false);
    return d[0];
}

// ---------------- Cooperative fused kernel ----------------
template <int RPW>
__global__ __launch_bounds__(256, 8) void k_coop(
    const float* __restrict__ hs, const float* __restrict__ res,
    const float* __restrict__ wg, const float* __restrict__ scale_p,
    float* __restrict__ q_dyn, float* __restrict__ resid_out,
    unsigned int* __restrict__ q8w, float* __restrict__ wsmax)
{
    __shared__ float smax[4];
    __shared__ float lut[256];

    const int t = threadIdx.x, lane = t & 63, wv = t >> 6;
    const int bid = blockIdx.x;
    const float s = scale_p[0];

    float lmax = 0.0f;

#pragma unroll 1
    for (int rr = 0; rr < RPW; ++rr) {
        const int row = bid * (4 * RPW) + wv * RPW + rr;
        const size_t base = (size_t)row * H_DIM;

        // Trip 1: stream, add, store residual, accumulate sum-of-squares.
        double ss = 0.0;
#pragma unroll
        for (int c = 0; c < 16; ++c) {
            const int col = c * 256 + lane * 4;
            const v4f hv = *(const v4f*)(hs + base + col);
            const v4f rv = *(const v4f*)(res + base + col);
            const v4f a = hv + rv;
            *(v4f*)(resid_out + base + col) = a;
            ss += (double)a.x * (double)a.x + (double)a.y * (double)a.y
                + (double)a.z * (double)a.z + (double)a.w * (double)a.w;
        }
#pragma unroll
        for (int o = 32; o > 0; o >>= 1) ss += __shfl_down(ss, o, 64);
        ss = __shfl(ss, 0, 64);
        const float inv = (float)(1.0 / sqrt(ss / (double)H_DIM + 1e-6));

        // Trip 2: re-read residual (cache-hot), static quant -> ws.
#pragma unroll
        for (int c = 0; c < 16; ++c) {
            const int col = c * 256 + lane * 4;
            const v4f a  = *(const v4f*)(resid_out + base + col);
            const v4f w4 = *(const v4f*)(wg + col);
            float q0 = (a.x * inv) * w4.x / s;
            float q1 = (a.y * inv) * w4.y / s;
            float q2 = (a.z * inv) * w4.z / s;
            float q3 = (a.w * inv) * w4.w / s;
            q0 = fminf(fmaxf(q0, -FP8_MAX_F), FP8_MAX_F);
            q1 = fminf(fmaxf(q1, -FP8_MAX_F), FP8_MAX_F);
            q2 = fminf(fmaxf(q2, -FP8_MAX_F), FP8_MAX_F);
            q3 = fminf(fmaxf(q3, -FP8_MAX_F), FP8_MAX_F);
            q8w[(base >> 2) + c * 64 + lane] = quant4(q0, q1, q2, q3);
            // max|deq| == roundtrip(max|q|): RNE quant monotone & symmetric.
            lmax = fmaxf(lmax, fmaxf(fmaxf(fabsf(q0), fabsf(q1)),
                                     fmaxf(fabsf(q2), fabsf(q3))));
        }
    }

    // Per-block max -> wsmax[bid] (plain store; fully rewritten every call).
#pragma unroll
    for (int o = 32; o > 0; o >>= 1) lmax = fmaxf(lmax, __shfl_down(lmax, o, 64));
    if (lane == 0) smax[wv] = lmax;
    __syncthreads();
    if (t == 0)
        wsmax[bid] = fmaxf(fmaxf(smax[0], smax[1]), fmaxf(smax[2], smax[3]));

    cg::this_grid().sync();

    // Global amax: every block reduces gridDim.x entries (8KB, L2-resident).
    {
        float m = 0.0f;
        const int nblk = gridDim.x;
        for (int i = t * 4; i < nblk; i += 1024) {
            const v4f v = *(const v4f*)(wsmax + i);
            m = fmaxf(fmaxf(m, fmaxf(v.x, v.y)), fmaxf(v.z, v.w));
        }
#pragma unroll
        for (int o = 32; o > 0; o >>= 1) m = fmaxf(m, __shfl_down(m, o, 64));
        if (lane == 0) smax[wv] = m;
        __syncthreads();
    }
    const float amax   = fp8_roundtrip1(fmaxf(fmaxf(smax[0], smax[1]),
                                              fmaxf(smax[2], smax[3])));
    const float dscale = fmaxf(amax, 1e-12f) / FP8_MAX_F;

    // Build the 256-entry byte->output LUT (exact per-element reference math:
    // deq = fp8(b); q = deq/dscale (true f32 div); clip; fp8 RNE; widen).
    {
        const float deq = fp8_byte_to_f32((unsigned int)t);
        float q = deq / dscale;
        q = fminf(fmaxf(q, -FP8_MAX_F), FP8_MAX_F);
        lut[t] = fp8_roundtrip1(q);
    }
    __syncthreads();

    // Pass 2: requant via LUT, coalesced v4f nt-stores.
#pragma unroll 1
    for (int rr = 0; rr < RPW; ++rr) {
        const int row = bid * (4 * RPW) + wv * RPW + rr;
        const size_t base = (size_t)row * H_DIM;
#pragma unroll
        for (int c = 0; c < 16; ++c) {
            const unsigned int pw = q8w[(base >> 2) + c * 64 + lane];
            v4f ov;
            ov.x = lut[pw & 0xff];
            ov.y = lut[(pw >> 8) & 0xff];
            ov.z = lut[(pw >> 16) & 0xff];
            ov.w = lut[pw >> 24];
            __builtin_nontemporal_store(ov, (v4f*)(q_dyn + base + c * 256 + lane * 4));
        }
    }
}

// ---------------- Fallback: R2's two-kernel path (proven, 128us) ----------------
__global__ __launch_bounds__(256) void k_rms_quant(
    const float* __restrict__ hs, const float* __restrict__ res,
    const float* __restrict__ w, const float* __restrict__ scale_p,
    float* __restrict__ resid_out, unsigned int* __restrict__ q8w,
    float* __restrict__ blockmax)
{
    const int row = blockIdx.x;
    const int t   = threadIdx.x;
    const size_t base  = (size_t)row * H_DIM;
    const size_t base4 = base >> 2;

    float4 a[4];
    double ss = 0.0;
#pragma unroll
    for (int c = 0; c < 4; ++c) {
        const int col = c * 1024 + t * 4;
        const float4 hv = *(const float4*)(hs + base + col);
        const float4 rv = *(const float4*)(res + base + col);
        float4 av;
        av.x = hv.x + rv.x; av.y = hv.y + rv.y;
        av.z = hv.z + rv.z; av.w = hv.w + rv.w;
        a[c] = av;
        *(float4*)(resid_out + base + col) = av;
        ss += (double)av.x * (double)av.x + (double)av.y * (double)av.y
            + (double)av.z * (double)av.z + (double)av.w * (double)av.w;
    }
    __shared__ double sred[4];
#pragma unroll
    for (int o = 32; o > 0; o >>= 1) ss += __shfl_down(ss, o, 64);
    const int lane = t & 63, wid = t >> 6;
    if (lane == 0) sred[wid] = ss;
    __syncthreads();
    if (t == 0) sred[0] = sred[0] + sred[1] + sred[2] + sred[3];
    __syncthreads();
    const float inv = (float)(1.0 / sqrt(sred[0] / (double)H_DIM + 1e-6));

    const float s = scale_p[0];
    float lmax = 0.0f;
#pragma unroll
    for (int c = 0; c < 4; ++c) {
        const int col = c * 1024 + t * 4;
        const float4 wv = *(const float4*)(w + col);
        const float4 av = a[c];
        float q0 = (av.x * inv) * wv.x / s;
        float q1 = (av.y * inv) * wv.y / s;
        float q2 = (av.z * inv) * wv.z / s;
        float q3 = (av.w * inv) * wv.w / s;
        q0 = fminf(fmaxf(q0, -FP8_MAX_F), FP8_MAX_F);
        q1 = fminf(fmaxf(q1, -FP8_MAX_F), FP8_MAX_F);
        q2 = fminf(fmaxf(q2, -FP8_MAX_F), FP8_MAX_F);
        q3 = fminf(fmaxf(q3, -FP8_MAX_F), FP8_MAX_F);
        q8w[base4 + c * 256 + t] = quant4(q0, q1, q2, q3);
        lmax = fmaxf(lmax, fmaxf(fmaxf(fabsf(q0), fabsf(q1)),
                                 fmaxf(fabsf(q2), fabsf(q3))));
    }
    __shared__ float smax[4];
#pragma unroll
    for (int o = 32; o > 0; o >>= 1) lmax = fmaxf(lmax, __shfl_down(lmax, o, 64));
    if (lane == 0) smax[wid] = lmax;
    __syncthreads();
    if (t == 0)
        blockmax[row] = fmaxf(fmaxf(smax[0], smax[1]), fmaxf(smax[2], smax[3]));
}

__global__ __launch_bounds__(256) void k_requant(
    const unsigned int* __restrict__ q8w,
    const float* __restrict__ blockmax, int nblk,
    float* __restrict__ out, size_t nwords)
{
    const int t = threadIdx.x;
    const int lane = t & 63, wid = t >> 6;
    float m = 0.0f;
    for (int i = t * 4; i < nblk; i += 256 * 4) {
        const float4 v = *(const float4*)(blockmax + i);
        m = fmaxf(fmaxf(m, fmaxf(v.x, v.y)), fmaxf(v.z, v.w));
    }
#pragma unroll
    for (int o = 32; o > 0; o >>= 1) m = fmaxf(m, __shfl_down(m, o, 64));
    __shared__ float sm[4];
    if (lane == 0) sm[wid] = m;
    __syncthreads();
    const float amax   = fp8_roundtrip1(fmaxf(fmaxf(sm[0], sm[1]), fmaxf(sm[2], sm[3])));
    const float dscale = fmaxf(amax, 1e-12f) / FP8_MAX_F;

    size_t i = ((size_t)blockIdx.x * 256 + t) * 2;
    const size_t stride = (size_t)gridDim.x * 256 * 2;
    for (; i + 1 < nwords; i += stride) {
        const uint2 pw = *(const uint2*)(q8w + i);
#pragma unroll
        for (int j = 0; j < 2; ++j) {
            const unsigned int wv = j ? pw.y : pw.x;
            const v2f lo = __builtin_amdgcn_cvt_pk_f32_fp8((int)wv, false);
            const v2f hi = __builtin_amdgcn_cvt_pk_f32_fp8((int)wv, true);
            float q0 = lo[0] / dscale, q1 = lo[1] / dscale;
            float q2 = hi[0] / dscale, q3 = hi[1] / dscale;
            q0 = fminf(fmaxf(q0, -FP8_MAX_F), FP8_MAX_F);
            q1 = fminf(fmaxf(q1, -FP8_MAX_F), FP8_MAX_F);
            q2 = fminf(fmaxf(q2, -FP8_MAX_F), FP8_MAX_F);
            q3 = fminf(fmaxf(q3, -FP8_MAX_F), FP8_MAX_F);
            const unsigned int rq = quant4(q0, q1, q2, q3);
            const v2f olo = __builtin_amdgcn_cvt_pk_f32_fp8((int)rq, false);
            const v2f ohi = __builtin_amdgcn_cvt_pk_f32_fp8((int)rq, true);
            *(float4*)(out + (i + j) * 4) = make_float4(olo[0], olo[1], ohi[0], ohi[1]);
        }
    }
}

extern "C" void kernel_launch(void* const* d_in, const int* in_sizes, int n_in,
                              void* d_out, int out_size, void* d_ws, size_t ws_size,
                              hipStream_t stream) {
    const float* hs    = (const float*)d_in[0];
    const float* res   = (const float*)d_in[1];
    const float* w     = (const float*)d_in[2];
    const float* scale = (const float*)d_in[3];
    const int Hn = in_sizes[2];           // 4096
    const int Tn = in_sizes[0] / Hn;      // 8192
    const size_t nelem  = (size_t)Tn * Hn;
    const size_t nwords = nelem / 4;

    float* q_dyn_out = (float*)d_out;
    float* resid_out = (float*)d_out + nelem;

    // ws layout (both paths): [ wsmax/blockmax: 2*Tn floats ][ q8: nelem bytes ]
    float* wsmax = (float*)d_ws;
    unsigned int* q8w = (unsigned int*)((float*)d_ws + 2 * Tn);

    const bool ws_ok = ws_size >= (size_t)2 * Tn * 4 + nelem;

    bool done = false;
    if (Hn == H_DIM && Tn == 8192 && ws_ok) {
        void* args[] = { (void*)&hs, (void*)&res, (void*)&w, (void*)&scale,
                         (void*)&q_dyn_out, (void*)&resid_out,
                         (void*)&q8w, (void*)&wsmax };
        // RPW=1: 2048 blocks (8/CU exact fit). If refused, RPW=2: 1024 blocks.
        hipError_t e = hipLaunchCooperativeKernel((const void*)k_coop<1>,
                                                  dim3(2048), dim3(256),
                                                  args, 0, stream);
        if (e != hipSuccess)
            e = hipLaunchCooperativeKernel((const void*)k_coop<2>,
                                           dim3(1024), dim3(256),
                                           args, 0, stream);
        done = (e == hipSuccess);
    }

    if (!done && ws_ok) {
        k_rms_quant<<<Tn, 256, 0, stream>>>(hs, res, w, scale,
                                            resid_out, q8w, wsmax);
        k_requant<<<2048, 256, 0, stream>>>(q8w, wsmax, Tn, q_dyn_out, nwords);
    }
}

// Round 7
// 240.520 us; speedup vs baseline: 1.7006x; 1.7006x over previous
//
#include <hip/hip_runtime.h>

// T=8192 rows, H=4096 cols, f32 inputs.
// Outputs concat: [ q_dyn (T*H, f32-widened fp8), residual_out (T*H, f32) ]
//
// Two-kernel plan (cooperative launch abandoned: R4/R5/R6 all capped at
// ~1.5 TB/s regardless of body; non-coop R2 hit 4.5 TB/s):
//  k1 (block-per-row): nt-load h,r -> add -> nt-store resid (128MB W),
//      f64 sumsq (1 barrier), static fp8 quant -> q8 words (32MB W, normal
//      store so k2 reads hit L2/L3), per-row max|q| -> blockmax (plain store).
//  k2 (4096 blocks): reduce blockmax (32KB, L2), requant q8 -> q_dyn
//      (128MB nt W). True f32 divides; HW RNE fp8 cvt both ways.

typedef float v2f __attribute__((ext_vector_type(2)));
typedef float v4f __attribute__((ext_vector_type(4)));

static constexpr int H_DIM = 4096;
#define FP8_MAX_F 448.0f

__device__ __forceinline__ unsigned int quant4(float q0, float q1, float q2, float q3) {
    unsigned int pk = 0;
    pk = __builtin_amdgcn_cvt_pk_fp8_f32(q0, q1, pk, false); // bytes 0,1
    pk = __builtin_amdgcn_cvt_pk_fp8_f32(q2, q3, pk, true);  // bytes 2,3
    return pk;
}

__device__ __forceinline__ float fp8_roundtrip1(float x) {
    unsigned int pk = __builtin_amdgcn_cvt_pk_fp8_f32(x, x, 0, false);
    v2f d = __builtin_amdgcn_cvt_pk_f32_fp8((int)pk, false);
    return d[0];
}

// --- Kernel 1: one block per row ---
__global__ __launch_bounds__(256, 8) void k_rms_quant(
    const float* __restrict__ hs, const float* __restrict__ res,
    const float* __restrict__ wg, const float* __restrict__ scale_p,
    float* __restrict__ resid_out, unsigned int* __restrict__ q8w,
    float* __restrict__ blockmax)
{
    __shared__ double sred[4];
    __shared__ float smax[4];

    const int row = blockIdx.x;
    const int t   = threadIdx.x;
    const int lane = t & 63, wv = t >> 6;
    const size_t base  = (size_t)row * H_DIM;   // floats
    const size_t base4 = base >> 2;             // q8 words

    v4f a[4];
    double ss = 0.0;
#pragma unroll
    for (int c = 0; c < 4; ++c) {
        const int col = c * 1024 + t * 4;
        const v4f hv = __builtin_nontemporal_load((const v4f*)(hs + base + col));
        const v4f rv = __builtin_nontemporal_load((const v4f*)(res + base + col));
        const v4f av = hv + rv;
        a[c] = av;
        __builtin_nontemporal_store(av, (v4f*)(resid_out + base + col));
        ss += (double)av.x * (double)av.x + (double)av.y * (double)av.y
            + (double)av.z * (double)av.z + (double)av.w * (double)av.w;
    }

    // Block sum-of-squares: wave shfl reduce, ONE barrier, broadcast sum.
#pragma unroll
    for (int o = 32; o > 0; o >>= 1) ss += __shfl_down(ss, o, 64);
    if (lane == 0) sred[wv] = ss;
    __syncthreads();
    const double tot = sred[0] + sred[1] + sred[2] + sred[3];
    const float inv = (float)(1.0 / sqrt(tot / (double)H_DIM + 1e-6));

    const float s = scale_p[0];
    float lmax = 0.0f;
#pragma unroll
    for (int c = 0; c < 4; ++c) {
        const int col = c * 1024 + t * 4;
        const v4f w4 = *(const v4f*)(wg + col);   // L1/L2-hot across blocks
        const v4f av = a[c];
        float q0 = (av.x * inv) * w4.x / s;
        float q1 = (av.y * inv) * w4.y / s;
        float q2 = (av.z * inv) * w4.z / s;
        float q3 = (av.w * inv) * w4.w / s;
        q0 = fminf(fmaxf(q0, -FP8_MAX_F), FP8_MAX_F);
        q1 = fminf(fmaxf(q1, -FP8_MAX_F), FP8_MAX_F);
        q2 = fminf(fmaxf(q2, -FP8_MAX_F), FP8_MAX_F);
        q3 = fminf(fmaxf(q3, -FP8_MAX_F), FP8_MAX_F);
        q8w[base4 + c * 256 + t] = quant4(q0, q1, q2, q3);  // normal store
        // max|deq| == roundtrip(max|q|): RNE quant monotone & symmetric.
        lmax = fmaxf(lmax, fmaxf(fmaxf(fabsf(q0), fabsf(q1)),
                                 fmaxf(fabsf(q2), fabsf(q3))));
    }

#pragma unroll
    for (int o = 32; o > 0; o >>= 1) lmax = fmaxf(lmax, __shfl_down(lmax, o, 64));
    if (lane == 0) smax[wv] = lmax;
    __syncthreads();
    if (t == 0)
        blockmax[row] = fmaxf(fmaxf(smax[0], smax[1]), fmaxf(smax[2], smax[3]));
}

// --- Kernel 2: reduce blockmax (L2), requant 16 bytes/thread/iter ---
__global__ __launch_bounds__(256, 8) void k_requant(
    const uint4* __restrict__ q8q,
    const float* __restrict__ blockmax, int nblk,
    float* __restrict__ out, size_t nquads)
{
    __shared__ float sm[4];
    const int t = threadIdx.x;
    const int lane = t & 63, wv = t >> 6;

    float m = 0.0f;
    for (int i = t * 4; i < nblk; i += 1024) {
        const v4f v = *(const v4f*)(blockmax + i);
        m = fmaxf(fmaxf(m, fmaxf(v.x, v.y)), fmaxf(v.z, v.w));
    }
#pragma unroll
    for (int o = 32; o > 0; o >>= 1) m = fmaxf(m, __shfl_down(m, o, 64));
    if (lane == 0) sm[wv] = m;
    __syncthreads();
    const float amax   = fp8_roundtrip1(fmaxf(fmaxf(sm[0], sm[1]),
                                              fmaxf(sm[2], sm[3])));
    const float dscale = fmaxf(amax, 1e-12f) / FP8_MAX_F;

    size_t i = (size_t)blockIdx.x * 256 + t;
    const size_t stride = (size_t)gridDim.x * 256;
    for (; i < nquads; i += stride) {
        const uint4 pq = q8q[i];
        const unsigned int ws[4] = { pq.x, pq.y, pq.z, pq.w };
#pragma unroll
        for (int j = 0; j < 4; ++j) {
            const unsigned int pw = ws[j];
            const v2f lo = __builtin_amdgcn_cvt_pk_f32_fp8((int)pw, false);
            const v2f hi = __builtin_amdgcn_cvt_pk_f32_fp8((int)pw, true);
            float q0 = lo[0] / dscale, q1 = lo[1] / dscale;
            float q2 = hi[0] / dscale, q3 = hi[1] / dscale;
            q0 = fminf(fmaxf(q0, -FP8_MAX_F), FP8_MAX_F);
            q1 = fminf(fmaxf(q1, -FP8_MAX_F), FP8_MAX_F);
            q2 = fminf(fmaxf(q2, -FP8_MAX_F), FP8_MAX_F);
            q3 = fminf(fmaxf(q3, -FP8_MAX_F), FP8_MAX_F);
            const unsigned int rq = quant4(q0, q1, q2, q3);
            const v2f olo = __builtin_amdgcn_cvt_pk_f32_fp8((int)rq, false);
            const v2f ohi = __builtin_amdgcn_cvt_pk_f32_fp8((int)rq, true);
            v4f ov; ov.x = olo[0]; ov.y = olo[1]; ov.z = ohi[0]; ov.w = ohi[1];
            __builtin_nontemporal_store(ov, (v4f*)(out + i * 16 + j * 4));
        }
    }
}

// --- Fallback kernels (ws too small for q8 intermediate) ---
__global__ __launch_bounds__(256) void k_rms_noq(
    const float* __restrict__ hs, const float* __restrict__ res,
    const float* __restrict__ wg, const float* __restrict__ scale_p,
    float* __restrict__ resid_out, float* __restrict__ inv_arr,
    float* __restrict__ blockmax)
{
    __shared__ double sred[4];
    __shared__ float smax[4];
    const int row = blockIdx.x;
    const int t = threadIdx.x;
    const int lane = t & 63, wv = t >> 6;
    const size_t base = (size_t)row * H_DIM;

    v4f a[4];
    double ss = 0.0;
#pragma unroll
    for (int c = 0; c < 4; ++c) {
        const int col = c * 1024 + t * 4;
        const v4f hv = *(const v4f*)(hs + base + col);
        const v4f rv = *(const v4f*)(res + base + col);
        const v4f av = hv + rv;
        a[c] = av;
        *(v4f*)(resid_out + base + col) = av;
        ss += (double)av.x * (double)av.x + (double)av.y * (double)av.y
            + (double)av.z * (double)av.z + (double)av.w * (double)av.w;
    }
#pragma unroll
    for (int o = 32; o > 0; o >>= 1) ss += __shfl_down(ss, o, 64);
    if (lane == 0) sred[wv] = ss;
    __syncthreads();
    const double tot = sred[0] + sred[1] + sred[2] + sred[3];
    const float inv = (float)(1.0 / sqrt(tot / (double)H_DIM + 1e-6));
    if (t == 0) inv_arr[row] = inv;

    const float s = scale_p[0];
    float lmax = 0.0f;
#pragma unroll
    for (int c = 0; c < 4; ++c) {
        const int col = c * 1024 + t * 4;
        const v4f w4 = *(const v4f*)(wg + col);
        const v4f av = a[c];
        float q0 = fminf(fmaxf((av.x * inv) * w4.x / s, -FP8_MAX_F), FP8_MAX_F);
        float q1 = fminf(fmaxf((av.y * inv) * w4.y / s, -FP8_MAX_F), FP8_MAX_F);
        float q2 = fminf(fmaxf((av.z * inv) * w4.z / s, -FP8_MAX_F), FP8_MAX_F);
        float q3 = fminf(fmaxf((av.w * inv) * w4.w / s, -FP8_MAX_F), FP8_MAX_F);
        lmax = fmaxf(lmax, fmaxf(fmaxf(fabsf(q0), fabsf(q1)),
                                 fmaxf(fabsf(q2), fabsf(q3))));
    }
#pragma unroll
    for (int o = 32; o > 0; o >>= 1) lmax = fmaxf(lmax, __shfl_down(lmax, o, 64));
    if (lane == 0) smax[wv] = lmax;
    __syncthreads();
    if (t == 0)
        blockmax[row] = fmaxf(fmaxf(smax[0], smax[1]), fmaxf(smax[2], smax[3]));
}

__global__ __launch_bounds__(256) void k_requant_rows(
    const float* __restrict__ resid_out, const float* __restrict__ wg,
    const float* __restrict__ scale_p, const float* __restrict__ inv_arr,
    const float* __restrict__ blockmax, int nblk, float* __restrict__ out)
{
    __shared__ float sm[4];
    const int row = blockIdx.x;
    const int t = threadIdx.x;
    const int lane = t & 63, wv = t >> 6;
    float m = 0.0f;
    for (int i = t * 4; i < nblk; i += 1024) {
        const v4f v = *(const v4f*)(blockmax + i);
        m = fmaxf(fmaxf(m, fmaxf(v.x, v.y)), fmaxf(v.z, v.w));
    }
#pragma unroll
    for (int o = 32; o > 0; o >>= 1) m = fmaxf(m, __shfl_down(m, o, 64));
    if (lane == 0) sm[wv] = m;
    __syncthreads();
    const float amax   = fp8_roundtrip1(fmaxf(fmaxf(sm[0], sm[1]), fmaxf(sm[2], sm[3])));
    const float dscale = fmaxf(amax, 1e-12f) / FP8_MAX_F;

    const size_t base = (size_t)row * H_DIM;
    const float inv = inv_arr[row];
    const float s = scale_p[0];
#pragma unroll
    for (int c = 0; c < 4; ++c) {
        const int col = c * 1024 + t * 4;
        const v4f av = *(const v4f*)(resid_out + base + col);
        const v4f w4 = *(const v4f*)(wg + col);
        float qs[4] = { (av.x * inv) * w4.x / s, (av.y * inv) * w4.y / s,
                        (av.z * inv) * w4.z / s, (av.w * inv) * w4.w / s };
        v4f ov;
#pragma unroll
        for (int j = 0; j < 4; ++j) {
            float q = fminf(fmaxf(qs[j], -FP8_MAX_F), FP8_MAX_F);
            q = fp8_roundtrip1(q) / dscale;
            q = fminf(fmaxf(q, -FP8_MAX_F), FP8_MAX_F);
            ov[j] = fp8_roundtrip1(q);
        }
        *(v4f*)(out + base + col) = ov;
    }
}

extern "C" void kernel_launch(void* const* d_in, const int* in_sizes, int n_in,
                              void* d_out, int out_size, void* d_ws, size_t ws_size,
                              hipStream_t stream) {
    const float* hs    = (const float*)d_in[0];
    const float* res   = (const float*)d_in[1];
    const float* w     = (const float*)d_in[2];
    const float* scale = (const float*)d_in[3];
    const int Hn = in_sizes[2];           // 4096
    const int Tn = in_sizes[0] / Hn;      // 8192
    const size_t nelem  = (size_t)Tn * Hn;
    const size_t nquads = nelem / 16;     // 16 fp8 bytes per uint4

    float* q_dyn_out = (float*)d_out;
    float* resid_out = (float*)d_out + nelem;

    // ws layout: [ blockmax: Tn floats ][ inv: Tn floats ][ q8: nelem bytes ]
    float* blockmax = (float*)d_ws;
    float* inv_arr  = (float*)d_ws + Tn;
    unsigned int* q8w = (unsigned int*)((float*)d_ws + 2 * Tn);

    if (ws_size >= (size_t)2 * Tn * 4 + nelem) {
        k_rms_quant<<<Tn, 256, 0, stream>>>(hs, res, w, scale,
                                            resid_out, q8w, blockmax);
        k_requant<<<4096, 256, 0, stream>>>((const uint4*)q8w, blockmax, Tn,
                                            q_dyn_out, nquads);
    } else {
        k_rms_noq<<<Tn, 256, 0, stream>>>(hs, res, w, scale,
                                          resid_out, inv_arr, blockmax);
        k_requant_rows<<<Tn, 256, 0, stream>>>(resid_out, w, scale, inv_arr,
                                               blockmax, Tn, q_dyn_out);
    }
}

// Round 8
// 103.028 us; speedup vs baseline: 3.9702x; 2.3345x over previous
//
#include <hip/hip_runtime.h>

// T=8192 rows, H=4096 cols, f32 inputs.
// Outputs concat: [ q_dyn (T*H, f32-widened fp8), residual_out (T*H, f32) ]
//
// Two-kernel plan:
//  k1 (block-per-row, ~60us measured R7 = its 416MB roofline):
//      nt-load h,r -> add -> nt-store resid, f64 sumsq (1 barrier),
//      static fp8 quant -> q8 words (normal store -> L2/L3-hot for k2),
//      per-row max|q| -> blockmax.
//  k2 (4096 blocks): reduce blockmax (L2), requant q8 -> q_dyn.
//      R7 lesson: 16B/lane at 64B lane-stride nt-stores caused 2.8x write
//      amplification (nt bypasses L2 merging). Now one q8 word per thread
//      per iter: lane l writes 16B at lane-stride 16B -> wave = 1KB
//      contiguous full-line stores.

typedef float v2f __attribute__((ext_vector_type(2)));
typedef float v4f __attribute__((ext_vector_type(4)));

static constexpr int H_DIM = 4096;
#define FP8_MAX_F 448.0f

__device__ __forceinline__ unsigned int quant4(float q0, float q1, float q2, float q3) {
    unsigned int pk = 0;
    pk = __builtin_amdgcn_cvt_pk_fp8_f32(q0, q1, pk, false); // bytes 0,1
    pk = __builtin_amdgcn_cvt_pk_fp8_f32(q2, q3, pk, true);  // bytes 2,3
    return pk;
}

__device__ __forceinline__ float fp8_roundtrip1(float x) {
    unsigned int pk = __builtin_amdgcn_cvt_pk_fp8_f32(x, x, 0, false);
    v2f d = __builtin_amdgcn_cvt_pk_f32_fp8((int)pk, false);
    return d[0];
}

// --- Kernel 1: one block per row (unchanged from R7) ---
__global__ __launch_bounds__(256, 8) void k_rms_quant(
    const float* __restrict__ hs, const float* __restrict__ res,
    const float* __restrict__ wg, const float* __restrict__ scale_p,
    float* __restrict__ resid_out, unsigned int* __restrict__ q8w,
    float* __restrict__ blockmax)
{
    __shared__ double sred[4];
    __shared__ float smax[4];

    const int row = blockIdx.x;
    const int t   = threadIdx.x;
    const int lane = t & 63, wv = t >> 6;
    const size_t base  = (size_t)row * H_DIM;   // floats
    const size_t base4 = base >> 2;             // q8 words

    v4f a[4];
    double ss = 0.0;
#pragma unroll
    for (int c = 0; c < 4; ++c) {
        const int col = c * 1024 + t * 4;
        const v4f hv = __builtin_nontemporal_load((const v4f*)(hs + base + col));
        const v4f rv = __builtin_nontemporal_load((const v4f*)(res + base + col));
        const v4f av = hv + rv;
        a[c] = av;
        __builtin_nontemporal_store(av, (v4f*)(resid_out + base + col));
        ss += (double)av.x * (double)av.x + (double)av.y * (double)av.y
            + (double)av.z * (double)av.z + (double)av.w * (double)av.w;
    }

    // Block sum-of-squares: wave shfl reduce, ONE barrier, broadcast sum.
#pragma unroll
    for (int o = 32; o > 0; o >>= 1) ss += __shfl_down(ss, o, 64);
    if (lane == 0) sred[wv] = ss;
    __syncthreads();
    const double tot = sred[0] + sred[1] + sred[2] + sred[3];
    const float inv = (float)(1.0 / sqrt(tot / (double)H_DIM + 1e-6));

    const float s = scale_p[0];
    float lmax = 0.0f;
#pragma unroll
    for (int c = 0; c < 4; ++c) {
        const int col = c * 1024 + t * 4;
        const v4f w4 = *(const v4f*)(wg + col);   // L1/L2-hot across blocks
        const v4f av = a[c];
        float q0 = (av.x * inv) * w4.x / s;
        float q1 = (av.y * inv) * w4.y / s;
        float q2 = (av.z * inv) * w4.z / s;
        float q3 = (av.w * inv) * w4.w / s;
        q0 = fminf(fmaxf(q0, -FP8_MAX_F), FP8_MAX_F);
        q1 = fminf(fmaxf(q1, -FP8_MAX_F), FP8_MAX_F);
        q2 = fminf(fmaxf(q2, -FP8_MAX_F), FP8_MAX_F);
        q3 = fminf(fmaxf(q3, -FP8_MAX_F), FP8_MAX_F);
        q8w[base4 + c * 256 + t] = quant4(q0, q1, q2, q3);  // normal store
        // max|deq| == roundtrip(max|q|): RNE quant monotone & symmetric.
        lmax = fmaxf(lmax, fmaxf(fmaxf(fabsf(q0), fabsf(q1)),
                                 fmaxf(fabsf(q2), fabsf(q3))));
    }

#pragma unroll
    for (int o = 32; o > 0; o >>= 1) lmax = fmaxf(lmax, __shfl_down(lmax, o, 64));
    if (lane == 0) smax[wv] = lmax;
    __syncthreads();
    if (t == 0)
        blockmax[row] = fmaxf(fmaxf(smax[0], smax[1]), fmaxf(smax[2], smax[3]));
}

// --- Kernel 2: reduce blockmax (L2), requant with fully-coalesced stores ---
__global__ __launch_bounds__(256, 8) void k_requant(
    const unsigned int* __restrict__ q8w,
    const float* __restrict__ blockmax, int nblk,
    float* __restrict__ out, size_t nwords)
{
    __shared__ float sm[4];
    const int t = threadIdx.x;
    const int lane = t & 63, wv = t >> 6;

    float m = 0.0f;
    for (int i = t * 4; i < nblk; i += 1024) {
        const v4f v = *(const v4f*)(blockmax + i);
        m = fmaxf(fmaxf(m, fmaxf(v.x, v.y)), fmaxf(v.z, v.w));
    }
#pragma unroll
    for (int o = 32; o > 0; o >>= 1) m = fmaxf(m, __shfl_down(m, o, 64));
    if (lane == 0) sm[wv] = m;
    __syncthreads();
    const float amax   = fp8_roundtrip1(fmaxf(fmaxf(sm[0], sm[1]),
                                              fmaxf(sm[2], sm[3])));
    const float dscale = fmaxf(amax, 1e-12f) / FP8_MAX_F;

    // One q8 word per thread per iteration: reads 4B/lane (256B/wave
    // contiguous), writes 16B/lane (1KB/wave contiguous full lines).
    size_t i = (size_t)blockIdx.x * 256 + t;
    const size_t stride = (size_t)gridDim.x * 256;
    for (; i < nwords; i += stride) {
        const unsigned int pw = q8w[i];
        const v2f lo = __builtin_amdgcn_cvt_pk_f32_fp8((int)pw, false);
        const v2f hi = __builtin_amdgcn_cvt_pk_f32_fp8((int)pw, true);
        float q0 = lo[0] / dscale, q1 = lo[1] / dscale;
        float q2 = hi[0] / dscale, q3 = hi[1] / dscale;
        q0 = fminf(fmaxf(q0, -FP8_MAX_F), FP8_MAX_F);
        q1 = fminf(fmaxf(q1, -FP8_MAX_F), FP8_MAX_F);
        q2 = fminf(fmaxf(q2, -FP8_MAX_F), FP8_MAX_F);
        q3 = fminf(fmaxf(q3, -FP8_MAX_F), FP8_MAX_F);
        const unsigned int rq = quant4(q0, q1, q2, q3);
        const v2f olo = __builtin_amdgcn_cvt_pk_f32_fp8((int)rq, false);
        const v2f ohi = __builtin_amdgcn_cvt_pk_f32_fp8((int)rq, true);
        v4f ov; ov.x = olo[0]; ov.y = olo[1]; ov.z = ohi[0]; ov.w = ohi[1];
        __builtin_nontemporal_store(ov, (v4f*)(out + i * 4));
    }
}

// --- Fallback kernels (ws too small for q8 intermediate) ---
__global__ __launch_bounds__(256) void k_rms_noq(
    const float* __restrict__ hs, const float* __restrict__ res,
    const float* __restrict__ wg, const float* __restrict__ scale_p,
    float* __restrict__ resid_out, float* __restrict__ inv_arr,
    float* __restrict__ blockmax)
{
    __shared__ double sred[4];
    __shared__ float smax[4];
    const int row = blockIdx.x;
    const int t = threadIdx.x;
    const int lane = t & 63, wv = t >> 6;
    const size_t base = (size_t)row * H_DIM;

    v4f a[4];
    double ss = 0.0;
#pragma unroll
    for (int c = 0; c < 4; ++c) {
        const int col = c * 1024 + t * 4;
        const v4f hv = *(const v4f*)(hs + base + col);
        const v4f rv = *(const v4f*)(res + base + col);
        const v4f av = hv + rv;
        a[c] = av;
        *(v4f*)(resid_out + base + col) = av;
        ss += (double)av.x * (double)av.x + (double)av.y * (double)av.y
            + (double)av.z * (double)av.z + (double)av.w * (double)av.w;
    }
#pragma unroll
    for (int o = 32; o > 0; o >>= 1) ss += __shfl_down(ss, o, 64);
    if (lane == 0) sred[wv] = ss;
    __syncthreads();
    const double tot = sred[0] + sred[1] + sred[2] + sred[3];
    const float inv = (float)(1.0 / sqrt(tot / (double)H_DIM + 1e-6));
    if (t == 0) inv_arr[row] = inv;

    const float s = scale_p[0];
    float lmax = 0.0f;
#pragma unroll
    for (int c = 0; c < 4; ++c) {
        const int col = c * 1024 + t * 4;
        const v4f w4 = *(const v4f*)(wg + col);
        const v4f av = a[c];
        float q0 = fminf(fmaxf((av.x * inv) * w4.x / s, -FP8_MAX_F), FP8_MAX_F);
        float q1 = fminf(fmaxf((av.y * inv) * w4.y / s, -FP8_MAX_F), FP8_MAX_F);
        float q2 = fminf(fmaxf((av.z * inv) * w4.z / s, -FP8_MAX_F), FP8_MAX_F);
        float q3 = fminf(fmaxf((av.w * inv) * w4.w / s, -FP8_MAX_F), FP8_MAX_F);
        lmax = fmaxf(lmax, fmaxf(fmaxf(fabsf(q0), fabsf(q1)),
                                 fmaxf(fabsf(q2), fabsf(q3))));
    }
#pragma unroll
    for (int o = 32; o > 0; o >>= 1) lmax = fmaxf(lmax, __shfl_down(lmax, o, 64));
    if (lane == 0) smax[wv] = lmax;
    __syncthreads();
    if (t == 0)
        blockmax[row] = fmaxf(fmaxf(smax[0], smax[1]), fmaxf(smax[2], smax[3]));
}

__global__ __launch_bounds__(256) void k_requant_rows(
    const float* __restrict__ resid_out, const float* __restrict__ wg,
    const float* __restrict__ scale_p, const float* __restrict__ inv_arr,
    const float* __restrict__ blockmax, int nblk, float* __restrict__ out)
{
    __shared__ float sm[4];
    const int row = blockIdx.x;
    const int t = threadIdx.x;
    const int lane = t & 63, wv = t >> 6;
    float m = 0.0f;
    for (int i = t * 4; i < nblk; i += 1024) {
        const v4f v = *(const v4f*)(blockmax + i);
        m = fmaxf(fmaxf(m, fmaxf(v.x, v.y)), fmaxf(v.z, v.w));
    }
#pragma unroll
    for (int o = 32; o > 0; o >>= 1) m = fmaxf(m, __shfl_down(m, o, 64));
    if (lane == 0) sm[wv] = m;
    __syncthreads();
    const float amax   = fp8_roundtrip1(fmaxf(fmaxf(sm[0], sm[1]), fmaxf(sm[2], sm[3])));
    const float dscale = fmaxf(amax, 1e-12f) / FP8_MAX_F;

    const size_t base = (size_t)row * H_DIM;
    const float inv = inv_arr[row];
    const float s = scale_p[0];
#pragma unroll
    for (int c = 0; c < 4; ++c) {
        const int col = c * 1024 + t * 4;
        const v4f av = *(const v4f*)(resid_out + base + col);
        const v4f w4 = *(const v4f*)(wg + col);
        float qs[4] = { (av.x * inv) * w4.x / s, (av.y * inv) * w4.y / s,
                        (av.z * inv) * w4.z / s, (av.w * inv) * w4.w / s };
        v4f ov;
#pragma unroll
        for (int j = 0; j < 4; ++j) {
            float q = fminf(fmaxf(qs[j], -FP8_MAX_F), FP8_MAX_F);
            q = fp8_roundtrip1(q) / dscale;
            q = fminf(fmaxf(q, -FP8_MAX_F), FP8_MAX_F);
            ov[j] = fp8_roundtrip1(q);
        }
        *(v4f*)(out + base + col) = ov;
    }
}

extern "C" void kernel_launch(void* const* d_in, const int* in_sizes, int n_in,
                              void* d_out, int out_size, void* d_ws, size_t ws_size,
                              hipStream_t stream) {
    const float* hs    = (const float*)d_in[0];
    const float* res   = (const float*)d_in[1];
    const float* w     = (const float*)d_in[2];
    const float* scale = (const float*)d_in[3];
    const int Hn = in_sizes[2];           // 4096
    const int Tn = in_sizes[0] / Hn;      // 8192
    const size_t nelem  = (size_t)Tn * Hn;
    const size_t nwords = nelem / 4;

    float* q_dyn_out = (float*)d_out;
    float* resid_out = (float*)d_out + nelem;

    // ws layout: [ blockmax: Tn floats ][ inv: Tn floats ][ q8: nelem bytes ]
    float* blockmax = (float*)d_ws;
    float* inv_arr  = (float*)d_ws + Tn;
    unsigned int* q8w = (unsigned int*)((float*)d_ws + 2 * Tn);

    if (ws_size >= (size_t)2 * Tn * 4 + nelem) {
        k_rms_quant<<<Tn, 256, 0, stream>>>(hs, res, w, scale,
                                            resid_out, q8w, blockmax);
        k_requant<<<4096, 256, 0, stream>>>(q8w, blockmax, Tn,
                                            q_dyn_out, nwords);
    } else {
        k_rms_noq<<<Tn, 256, 0, stream>>>(hs, res, w, scale,
                                          resid_out, inv_arr, blockmax);
        k_requant_rows<<<Tn, 256, 0, stream>>>(resid_out, w, scale, inv_arr,
                                               blockmax, Tn, q_dyn_out);
    }
}